// Round 1
// baseline (110.465 us; speedup 1.0000x reference)
//
#include <hip/hip_runtime.h>
#include <math.h>

// RoPE, interleaved layout: x shape (4, 16, 4096, 64) fp32.
// out[..., 2i]   = cos(a_i)*x[2i] - sin(a_i)*x[2i+1]
// out[..., 2i+1] = sin(a_i)*x[2i] + cos(a_i)*x[2i+1]
// a_i = pos * 10000^(-i/32), pos = seq index (reference ignores token_positions).
//
// Memory-bound elementwise: float4 per thread = 2 pairs, 16 B/lane coalesced.

#define N_ELEMS (4 * 16 * 4096 * 64)
#define N_FLOAT4 (N_ELEMS / 4)

__global__ __launch_bounds__(256) void
rope_kernel(const float4* __restrict__ x, float4* __restrict__ out, int n4) {
    int t = blockIdx.x * blockDim.x + threadIdx.x;
    if (t >= n4) return;

    float4 v = x[t];

    // flat element index of v.x
    unsigned e = (unsigned)t << 2;
    unsigned d = e & 63u;                 // offset within head dim, multiple of 4
    unsigned pos = (e >> 6) & 4095u;      // sequence position
    float fpos = (float)pos;

    // pair indices for (v.x,v.y) and (v.z,v.w)
    float p0 = (float)(d >> 1);
    float p1 = p0 + 1.0f;

    // inv_freq = 10000^(-p/32) = exp2(-p * log2(10000)/32)
    const float kNegLog2ThetaOver32 = -0.41524101186092503f; // -log2(10000)/32
    float ang0 = fpos * exp2f(p0 * kNegLog2ThetaOver32);
    float ang1 = fpos * exp2f(p1 * kNegLog2ThetaOver32);

    float s0, c0, s1, c1;
    sincosf(ang0, &s0, &c0);
    sincosf(ang1, &s1, &c1);

    float4 r;
    r.x = c0 * v.x - s0 * v.y;
    r.y = s0 * v.x + c0 * v.y;
    r.z = c1 * v.z - s1 * v.w;
    r.w = s1 * v.z + c1 * v.w;
    out[t] = r;
}

extern "C" void kernel_launch(void* const* d_in, const int* in_sizes, int n_in,
                              void* d_out, int out_size, void* d_ws, size_t ws_size,
                              hipStream_t stream) {
    const float4* x = (const float4*)d_in[0];
    float4* out = (float4*)d_out;
    int n4 = out_size / 4;  // 16,777,216 / 4 = 4,194,304

    const int block = 256;
    const int grid = (n4 + block - 1) / block;  // 16384
    rope_kernel<<<grid, block, 0, stream>>>(x, out, n4);
}

// Round 2
// 110.293 us; speedup vs baseline: 1.0016x; 1.0016x over previous
//
#include <hip/hip_runtime.h>
#include <math.h>

// RoPE, interleaved layout: x shape (4, 16, 4096, 64) fp32.
// out[..., 2i]   = cos(a_i)*x[2i] - sin(a_i)*x[2i+1]
// out[..., 2i+1] = sin(a_i)*x[2i] + cos(a_i)*x[2i+1]
// a_i = pos * 10000^(-i/32), pos = seq index (reference ignores token_positions).
//
// Memory-bound target: float4/lane (16 B) coalesced; transcendentals via
// hardware v_sin_f32/v_cos_f32 (input in REVOLUTIONS — fold 1/2π into
// inv_freq, fract-reduce with floorf). Threshold is 0.115 absmax; hw-sin
// path adds ~5e-3 worst-case — safe.

__global__ __launch_bounds__(256) void
rope_kernel(const float4* __restrict__ x, float4* __restrict__ out, int n4) {
    int t = blockIdx.x * blockDim.x + threadIdx.x;
    if (t >= n4) return;

    float4 v = x[t];

    // flat element index of v.x
    unsigned e = (unsigned)t << 2;
    unsigned d = e & 63u;                 // offset within head dim (multiple of 4)
    unsigned pos = (e >> 6) & 4095u;      // sequence position
    float fpos = (float)pos;

    // pair index for (v.x,v.y); (v.z,v.w) is p0+1
    float p0 = (float)(d >> 1);

    // inv_freq in REVOLUTIONS: 10000^(-p/32) / (2*pi)
    //   = exp2( p * (-log2(10000)/32) - log2(2*pi) )
    const float kA = -0.41524101186092503f;  // -log2(10000)/32
    const float kB = -2.6514961294723187f;   // -log2(2*pi)
    float invf0 = exp2f(fmaf(p0, kA, kB));
    const float kStep = 0.7498942093324559f; // 10000^(-1/32)
    float invf1 = invf0 * kStep;

    // angle in revolutions, fract-reduced (pos >= 0 so floorf == fract)
    float r0 = fpos * invf0; r0 -= floorf(r0);
    float r1 = fpos * invf1; r1 -= floorf(r1);

    // hardware sin/cos: D = sin(S0 * 2*pi)
    float s0 = __builtin_amdgcn_sinf(r0);
    float c0 = __builtin_amdgcn_cosf(r0);
    float s1 = __builtin_amdgcn_sinf(r1);
    float c1 = __builtin_amdgcn_cosf(r1);

    float4 r;
    r.x = c0 * v.x - s0 * v.y;
    r.y = s0 * v.x + c0 * v.y;
    r.z = c1 * v.z - s1 * v.w;
    r.w = s1 * v.z + c1 * v.w;
    out[t] = r;
}

extern "C" void kernel_launch(void* const* d_in, const int* in_sizes, int n_in,
                              void* d_out, int out_size, void* d_ws, size_t ws_size,
                              hipStream_t stream) {
    const float4* x = (const float4*)d_in[0];
    float4* out = (float4*)d_out;
    int n4 = out_size / 4;  // 16,777,216 / 4 = 4,194,304

    const int block = 256;
    const int grid = (n4 + block - 1) / block;  // 16384
    rope_kernel<<<grid, block, 0, stream>>>(x, out, n4);
}